// Round 1
// baseline (286.008 us; speedup 1.0000x reference)
//
#include <hip/hip_runtime.h>
#include <math.h>

#define BB 4
#define SS 1024
#define DM 768
#define HH 12
#define DEPTH 64

// ---------------- Kernel 1: shared projections qh/kh/vh ----------------
// One block per (b,s) row. 192 threads = 3 waves; wave m computes matrix m.
__global__ __launch_bounds__(192) void proj_kernel(
    const float* __restrict__ q, const float* __restrict__ k, const float* __restrict__ v,
    const float* __restrict__ Wq, const float* __restrict__ bq,
    const float* __restrict__ Wk, const float* __restrict__ bk,
    const float* __restrict__ Wv, const float* __restrict__ bv,
    float* __restrict__ qh, float* __restrict__ kh, float* __restrict__ vh)
{
    __shared__ float rows[3][DM];
    const int row = blockIdx.x;            // b*S + s
    const int t = threadIdx.x;             // 0..191
    const size_t base = (size_t)row * DM;
    for (int i = t; i < DM; i += 192) {
        rows[0][i] = q[base + i];
        rows[1][i] = k[base + i];
        rows[2][i] = v[base + i];
    }
    __syncthreads();
    const int m = t / DEPTH;               // 0..2 (wave-uniform)
    const int d = t % DEPTH;
    const float* W    = (m == 0) ? Wq : (m == 1) ? Wk : Wv;
    const float* bias = (m == 0) ? bq : (m == 1) ? bk : bv;
    float acc = bias[d];
    const float* r = rows[m];
    #pragma unroll 8
    for (int i = 0; i < DM; ++i)
        acc = fmaf(r[i], W[i * DEPTH + d], acc);
    float* dst = (m == 0) ? qh : (m == 1) ? kh : vh;
    dst[(size_t)row * DEPTH + d] = acc;
}

// ---------------- Kernel 2: Wc_red[d][j] = sum_h Wc[h*64+d][j] ----------------
__global__ __launch_bounds__(256) void wcred_kernel(
    const float* __restrict__ Wc, float* __restrict__ Wr)
{
    int idx = blockIdx.x * 256 + threadIdx.x;     // 0 .. 64*768-1
    if (idx >= DEPTH * DM) return;
    int d = idx / DM, j = idx % DM;
    float s = 0.f;
    #pragma unroll
    for (int h = 0; h < HH; ++h)
        s += Wc[(size_t)(h * DEPTH + d) * DM + j];
    Wr[idx] = s;
}

__device__ inline float wave_max64(float x) {
    #pragma unroll
    for (int off = 32; off > 0; off >>= 1) x = fmaxf(x, __shfl_xor(x, off));
    return x;
}
__device__ inline float wave_sum64(float x) {
    #pragma unroll
    for (int off = 32; off > 0; off >>= 1) x += __shfl_xor(x, off);
    return x;
}

// ---------------- Kernel 3: fused attention + output GEMM ----------------
// One block per (b, qi). 256 threads.
__global__ __launch_bounds__(256) void attn_kernel(
    const float* __restrict__ qh, const float* __restrict__ kh, const float* __restrict__ vh,
    const float* __restrict__ Wr, const float* __restrict__ bc,
    float* __restrict__ out, float* __restrict__ attn)
{
    __shared__ __align__(16) float w[SS];          // scores -> weights
    __shared__ float qrow[DEPTH];
    __shared__ float red[4];
    __shared__ float part[4][DEPTH];
    __shared__ float oh[DEPTH];

    const int bq_ = blockIdx.x;                    // b*S + qi
    const int b = bq_ >> 10;
    const int qi = bq_ & (SS - 1);
    const int t = threadIdx.x;

    if (t < DEPTH) qrow[t] = qh[(size_t)bq_ * DEPTH + t];
    __syncthreads();

    const float scale = 0.28867513459481287f;      // 1/sqrt(H=12)
    const float* khb = kh + (size_t)b * SS * DEPTH;

    // ---- scores: w[kk] = scale * dot(qrow, kh[b,kk,:]) ----
    for (int kk = t; kk < SS; kk += 256) {
        const float4* kr = (const float4*)(khb + (size_t)kk * DEPTH);
        float acc = 0.f;
        #pragma unroll
        for (int i = 0; i < DEPTH / 4; ++i) {
            float4 k4 = kr[i];
            acc = fmaf(qrow[4 * i + 0], k4.x, acc);
            acc = fmaf(qrow[4 * i + 1], k4.y, acc);
            acc = fmaf(qrow[4 * i + 2], k4.z, acc);
            acc = fmaf(qrow[4 * i + 3], k4.w, acc);
        }
        w[kk] = acc * scale;
    }
    __syncthreads();

    // ---- block max ----
    float lm = -INFINITY;
    for (int kk = t; kk < SS; kk += 256) lm = fmaxf(lm, w[kk]);
    lm = wave_max64(lm);
    const int wid = t >> 6;
    if ((t & 63) == 0) red[wid] = lm;
    __syncthreads();
    const float mx = fmaxf(fmaxf(red[0], red[1]), fmaxf(red[2], red[3]));
    __syncthreads();   // red will be reused

    // ---- exp + block sum ----
    float ls = 0.f;
    for (int kk = t; kk < SS; kk += 256) {
        float e = __expf(w[kk] - mx);
        w[kk] = e;
        ls += e;
    }
    ls = wave_sum64(ls);
    if ((t & 63) == 0) red[wid] = ls;
    __syncthreads();
    const float inv = 1.f / (red[0] + red[1] + red[2] + red[3]);

    // ---- normalize (own indices only) ----
    for (int kk = t; kk < SS; kk += 256) w[kk] *= inv;
    __syncthreads();

    // ---- write H identical weight rows, float4-coalesced ----
    {
        float* ap = attn + ((size_t)(b * HH) * SS + qi) * SS;
        const float4* w4 = (const float4*)w;
        float4 val = w4[t];                         // SS/4 == 256 == blockDim
        #pragma unroll
        for (int h = 0; h < HH; ++h)
            ((float4*)(ap + (size_t)h * SS * SS))[t] = val;
    }

    // ---- oh = weights @ vh  (wave 'seg' covers 256 k's) ----
    {
        const int d = t & 63, seg = t >> 6;
        const float* vb = vh + (size_t)b * SS * DEPTH;
        float acc = 0.f;
        const int k0 = seg * 256;
        for (int kk = k0; kk < k0 + 256; ++kk)
            acc = fmaf(w[kk], vb[(size_t)kk * DEPTH + d], acc);
        part[seg][d] = acc;
    }
    __syncthreads();
    if (t < DEPTH) oh[t] = part[0][t] + part[1][t] + part[2][t] + part[3][t];
    __syncthreads();

    // ---- out row = oh @ Wc_red + bc ----
    {
        float* orow = out + (size_t)bq_ * DM;
        for (int j = t; j < DM; j += 256) {
            float acc = bc[j];
            #pragma unroll 8
            for (int d2 = 0; d2 < DEPTH; ++d2)
                acc = fmaf(oh[d2], Wr[d2 * DM + j], acc);
            orow[j] = acc;
        }
    }
}

extern "C" void kernel_launch(void* const* d_in, const int* in_sizes, int n_in,
                              void* d_out, int out_size, void* d_ws, size_t ws_size,
                              hipStream_t stream) {
    const float* q  = (const float*)d_in[0];
    const float* k  = (const float*)d_in[1];
    const float* v  = (const float*)d_in[2];
    const float* Wq = (const float*)d_in[3];
    const float* bq = (const float*)d_in[4];
    const float* Wk = (const float*)d_in[5];
    const float* bk = (const float*)d_in[6];
    const float* Wv = (const float*)d_in[7];
    const float* bv = (const float*)d_in[8];
    const float* Wc = (const float*)d_in[9];
    const float* bc = (const float*)d_in[10];

    float* out  = (float*)d_out;                              // [B,S,DM]
    float* attn = out + (size_t)BB * SS * DM;                 // [B,H,S,S]

    float* ws = (float*)d_ws;
    const size_t NPROJ = (size_t)BB * SS * DEPTH;             // 262144
    float* qh = ws;
    float* kh = ws + NPROJ;
    float* vh = ws + 2 * NPROJ;
    float* Wr = ws + 3 * NPROJ;                               // 64*768

    proj_kernel<<<BB * SS, 192, 0, stream>>>(q, k, v, Wq, bq, Wk, bk, Wv, bv, qh, kh, vh);
    wcred_kernel<<<(DEPTH * DM + 255) / 256, 256, 0, stream>>>(Wc, Wr);
    attn_kernel<<<BB * SS, 256, 0, stream>>>(qh, kh, vh, Wr, bc, out, attn);
}

// Round 3
// 125.884 us; speedup vs baseline: 2.2720x; 2.2720x over previous
//
#include <hip/hip_runtime.h>
#include <math.h>

#define BB 4
#define SS 1024
#define DM 768
#define HH 12
#define DEPTH 64
#define QBLK 8
#define PROWS 16

typedef float vfloat4 __attribute__((ext_vector_type(4)));

__device__ inline float wave_max64(float x) {
    #pragma unroll
    for (int off = 32; off > 0; off >>= 1) x = fmaxf(x, __shfl_xor(x, off));
    return x;
}
__device__ inline float wave_sum64(float x) {
    #pragma unroll
    for (int off = 32; off > 0; off >>= 1) x += __shfl_xor(x, off);
    return x;
}

// ---------------- Kernel 1: projections. One matrix per block, PROWS rows ----------------
__global__ __launch_bounds__(256, 3) void proj_kernel(
    const float* __restrict__ q, const float* __restrict__ k, const float* __restrict__ v,
    const float* __restrict__ Wq, const float* __restrict__ bq,
    const float* __restrict__ Wk, const float* __restrict__ bk,
    const float* __restrict__ Wv, const float* __restrict__ bv,
    float* __restrict__ qh, float* __restrict__ kh, float* __restrict__ vh)
{
    __shared__ __align__(16) float rows[PROWS][DM];    // 48 KB
    const int nrb  = (BB * SS) / PROWS;                // 256
    const int m    = blockIdx.x / nrb;
    const int rb   = blockIdx.x % nrb;
    const int row0 = rb * PROWS;
    const int t    = threadIdx.x;

    const float* src  = (m == 0) ? q  : (m == 1) ? k  : v;
    const float* W    = (m == 0) ? Wq : (m == 1) ? Wk : Wv;
    const float* bias = (m == 0) ? bq : (m == 1) ? bk : bv;
    float* dst        = (m == 0) ? qh : (m == 1) ? kh : vh;

    const float4* s4 = (const float4*)(src + (size_t)row0 * DM);
    float4* r4 = (float4*)&rows[0][0];
    for (int i = t; i < PROWS * DM / 4; i += 256) r4[i] = s4[i];
    __syncthreads();

    const int d  = t & 63;
    const int rg = t >> 6;                              // 0..3 -> rows rg*4..rg*4+3
    const float* Wp = W + d;
    float a0 = bias[d], a1 = a0, a2 = a0, a3 = a0;
    #pragma unroll 8
    for (int i = 0; i < DM; i += 4) {
        const float wv0 = Wp[(size_t)(i + 0) * DEPTH];
        const float wv1 = Wp[(size_t)(i + 1) * DEPTH];
        const float wv2 = Wp[(size_t)(i + 2) * DEPTH];
        const float wv3 = Wp[(size_t)(i + 3) * DEPTH];
        const float4 r0 = *(const float4*)&rows[rg * 4 + 0][i];
        const float4 r1 = *(const float4*)&rows[rg * 4 + 1][i];
        const float4 r2 = *(const float4*)&rows[rg * 4 + 2][i];
        const float4 r3 = *(const float4*)&rows[rg * 4 + 3][i];
        a0 = fmaf(r0.x, wv0, a0); a0 = fmaf(r0.y, wv1, a0); a0 = fmaf(r0.z, wv2, a0); a0 = fmaf(r0.w, wv3, a0);
        a1 = fmaf(r1.x, wv0, a1); a1 = fmaf(r1.y, wv1, a1); a1 = fmaf(r1.z, wv2, a1); a1 = fmaf(r1.w, wv3, a1);
        a2 = fmaf(r2.x, wv0, a2); a2 = fmaf(r2.y, wv1, a2); a2 = fmaf(r2.z, wv2, a2); a2 = fmaf(r2.w, wv3, a2);
        a3 = fmaf(r3.x, wv0, a3); a3 = fmaf(r3.y, wv1, a3); a3 = fmaf(r3.z, wv2, a3); a3 = fmaf(r3.w, wv3, a3);
    }
    float* dp = dst + (size_t)(row0 + rg * 4) * DEPTH + d;
    dp[0] = a0; dp[DEPTH] = a1; dp[2 * DEPTH] = a2; dp[3 * DEPTH] = a3;
}

// ---------------- Kernel 2: Wc_red[d][j] = sum_h Wc[h*64+d][j] ----------------
__global__ __launch_bounds__(256) void wcred_kernel(
    const float* __restrict__ Wc, float* __restrict__ Wr)
{
    int idx = blockIdx.x * 256 + threadIdx.x;
    if (idx >= DEPTH * DM) return;
    int d = idx / DM, j = idx % DM;
    float s = 0.f;
    #pragma unroll
    for (int h = 0; h < HH; ++h)
        s += Wc[(size_t)(h * DEPTH + d) * DM + j];
    Wr[idx] = s;
}

// ---------------- Kernel 3: fused attention, QBLK q-rows per block ----------------
__global__ __launch_bounds__(512, 4) void attn_kernel(
    const float* __restrict__ qh, const float* __restrict__ kh, const float* __restrict__ vh,
    const float* __restrict__ Wr, const float* __restrict__ bc,
    float* __restrict__ out, float* __restrict__ attn)
{
    __shared__ __align__(16) float w[QBLK][SS];          // 32 KB
    __shared__ __align__(16) float qrows[QBLK][DEPTH];   // 2 KB
    __shared__ __align__(16) float part[QBLK][8][DEPTH]; // 16 KB
    __shared__ __align__(16) float ohT[DEPTH][QBLK];     // 2 KB

    const int blk = blockIdx.x;                          // b*(S/QBLK) + qt
    const int b   = blk >> 7;                            // 128 blocks per batch
    const int qi0 = (blk & 127) * QBLK;
    const int t    = threadIdx.x;
    const int lane = t & 63, wid = t >> 6;

    qrows[t >> 6][t & 63] = qh[((size_t)b * SS + qi0 + (t >> 6)) * DEPTH + (t & 63)];
    __syncthreads();

    const float scale = 0.28867513459481287f;            // 1/sqrt(H=12)
    const float* khb = kh + (size_t)b * SS * DEPTH;
    const float* vb  = vh + (size_t)b * SS * DEPTH;

    // ---- scores: each thread computes kk = t and kk = t+512 for all 8 rows ----
    {
        float acc0[QBLK], acc1[QBLK];
        #pragma unroll
        for (int r = 0; r < QBLK; ++r) { acc0[r] = 0.f; acc1[r] = 0.f; }
        const float4* kb0 = (const float4*)(khb + (size_t)t * DEPTH);
        const float4* kb1 = (const float4*)(khb + (size_t)(t + 512) * DEPTH);
        #pragma unroll
        for (int i = 0; i < DEPTH / 4; ++i) {
            const float4 k0 = kb0[i];
            const float4 k1 = kb1[i];
            #pragma unroll
            for (int r = 0; r < QBLK; ++r) {
                const float4 q4 = *(const float4*)&qrows[r][4 * i];
                acc0[r] = fmaf(q4.x, k0.x, acc0[r]); acc0[r] = fmaf(q4.y, k0.y, acc0[r]);
                acc0[r] = fmaf(q4.z, k0.z, acc0[r]); acc0[r] = fmaf(q4.w, k0.w, acc0[r]);
                acc1[r] = fmaf(q4.x, k1.x, acc1[r]); acc1[r] = fmaf(q4.y, k1.y, acc1[r]);
                acc1[r] = fmaf(q4.z, k1.z, acc1[r]); acc1[r] = fmaf(q4.w, k1.w, acc1[r]);
            }
        }
        #pragma unroll
        for (int r = 0; r < QBLK; ++r) {
            w[r][t]       = acc0[r] * scale;
            w[r][t + 512] = acc1[r] * scale;
        }
    }
    __syncthreads();

    // ---- softmax: wave wid owns row wid; values held in registers ----
    {
        float* wr = w[wid];
        float e[16];
        float lm = -INFINITY;
        #pragma unroll
        for (int j2 = 0; j2 < 16; ++j2) { e[j2] = wr[lane + 64 * j2]; lm = fmaxf(lm, e[j2]); }
        lm = wave_max64(lm);
        float ls = 0.f;
        #pragma unroll
        for (int j2 = 0; j2 < 16; ++j2) { e[j2] = __expf(e[j2] - lm); ls += e[j2]; }
        ls = wave_sum64(ls);
        const float inv = 1.f / ls;
        #pragma unroll
        for (int j2 = 0; j2 < 16; ++j2) wr[lane + 64 * j2] = e[j2] * inv;
    }
    __syncthreads();

    // ---- PV: wave wid covers kk in [wid*128, wid*128+128), all 8 rows ----
    {
        const float* vcol = vb + lane;
        float a[QBLK];
        #pragma unroll
        for (int r = 0; r < QBLK; ++r) a[r] = 0.f;
        const int kkbase = wid * 128;
        for (int j = 0; j < 32; ++j) {
            const int kk0 = kkbase + 4 * j;
            const float vf0 = vcol[(size_t)(kk0 + 0) * DEPTH];
            const float vf1 = vcol[(size_t)(kk0 + 1) * DEPTH];
            const float vf2 = vcol[(size_t)(kk0 + 2) * DEPTH];
            const float vf3 = vcol[(size_t)(kk0 + 3) * DEPTH];
            #pragma unroll
            for (int r = 0; r < QBLK; ++r) {
                const float4 w4 = *(const float4*)&w[r][kk0];   // LDS broadcast
                a[r] = fmaf(w4.x, vf0, a[r]); a[r] = fmaf(w4.y, vf1, a[r]);
                a[r] = fmaf(w4.z, vf2, a[r]); a[r] = fmaf(w4.w, vf3, a[r]);
            }
        }
        #pragma unroll
        for (int r = 0; r < QBLK; ++r) part[r][wid][lane] = a[r];
    }
    __syncthreads();

    // ---- reduce partials into transposed oh ----
    {
        const int d = t >> 3, r = t & 7;
        float s = 0.f;
        #pragma unroll
        for (int seg = 0; seg < 8; ++seg) s += part[r][seg][d];
        ohT[d][r] = s;
    }
    __syncthreads();

    // ---- attention-weights write: 12 nontemporal copies of each row ----
    {
        float* ap = attn + (((size_t)b * HH) * SS + (qi0 + wid)) * SS;
        const vfloat4* w4row = (const vfloat4*)&w[wid][0];
        const vfloat4 v0 = w4row[lane], v1 = w4row[lane + 64], v2 = w4row[lane + 128], v3 = w4row[lane + 192];
        #pragma unroll
        for (int h = 0; h < HH; ++h) {
            vfloat4* dstp = (vfloat4*)(ap + (size_t)h * SS * SS);
            __builtin_nontemporal_store(v0, dstp + lane);
            __builtin_nontemporal_store(v1, dstp + lane + 64);
            __builtin_nontemporal_store(v2, dstp + lane + 128);
            __builtin_nontemporal_store(v3, dstp + lane + 192);
        }
    }

    // ---- out rows = ohT @ Wr + bc ----
    {
        for (int j = t; j < DM; j += 512) {
            float a[QBLK];
            const float bj = bc[j];
            #pragma unroll
            for (int r = 0; r < QBLK; ++r) a[r] = bj;
            const float* wc = Wr + j;
            #pragma unroll 16
            for (int d2 = 0; d2 < DEPTH; ++d2) {
                const float wv = wc[(size_t)d2 * DM];
                const float4 o0 = *(const float4*)&ohT[d2][0];
                const float4 o1 = *(const float4*)&ohT[d2][4];
                a[0] = fmaf(o0.x, wv, a[0]); a[1] = fmaf(o0.y, wv, a[1]);
                a[2] = fmaf(o0.z, wv, a[2]); a[3] = fmaf(o0.w, wv, a[3]);
                a[4] = fmaf(o1.x, wv, a[4]); a[5] = fmaf(o1.y, wv, a[5]);
                a[6] = fmaf(o1.z, wv, a[6]); a[7] = fmaf(o1.w, wv, a[7]);
            }
            float* ob = out + ((size_t)b * SS + qi0) * DM + j;
            #pragma unroll
            for (int r = 0; r < QBLK; ++r)
                __builtin_nontemporal_store(a[r], ob + (size_t)r * DM);
        }
    }
}

extern "C" void kernel_launch(void* const* d_in, const int* in_sizes, int n_in,
                              void* d_out, int out_size, void* d_ws, size_t ws_size,
                              hipStream_t stream) {
    const float* q  = (const float*)d_in[0];
    const float* k  = (const float*)d_in[1];
    const float* v  = (const float*)d_in[2];
    const float* Wq = (const float*)d_in[3];
    const float* bq = (const float*)d_in[4];
    const float* Wk = (const float*)d_in[5];
    const float* bk = (const float*)d_in[6];
    const float* Wv = (const float*)d_in[7];
    const float* bv = (const float*)d_in[8];
    const float* Wc = (const float*)d_in[9];
    const float* bc = (const float*)d_in[10];

    float* out  = (float*)d_out;                              // [B,S,DM]
    float* attn = out + (size_t)BB * SS * DM;                 // [B,H,S,S]

    float* ws = (float*)d_ws;
    const size_t NPROJ = (size_t)BB * SS * DEPTH;             // 262144
    float* qh = ws;
    float* kh = ws + NPROJ;
    float* vh = ws + 2 * NPROJ;
    float* Wr = ws + 3 * NPROJ;                               // 64*768

    proj_kernel<<<3 * (BB * SS / PROWS), 256, 0, stream>>>(q, k, v, Wq, bq, Wk, bk, Wv, bv, qh, kh, vh);
    wcred_kernel<<<(DEPTH * DM + 255) / 256, 256, 0, stream>>>(Wc, Wr);
    attn_kernel<<<BB * (SS / QBLK), 512, 0, stream>>>(qh, kh, vh, Wr, bc, out, attn);
}